// Round 2
// baseline (88.006 us; speedup 1.0000x reference)
//
#include <hip/hip_runtime.h>

constexpr int B = 512;
// log2(e) / tau  with tau = 0.01
constexpr float C = 144.26950408889634f;

__global__ __launch_bounds__(512) void smoothap_rows(const float* __restrict__ scores,
                                                     const float* __restrict__ target,
                                                     float* __restrict__ ap_out) {
    const int q = blockIdx.x;
    const int i = threadIdx.x;
    const float* __restrict__ srow = scores + q * B;
    const float* __restrict__ trow = target + q * B;

    const float s_i = srow[i];   // divergent (vector load)
    const float t_i = trow[i];
    const float sic = s_i * C;

    // sigmoid((s_j - s_i)/tau) = 1 / (1 + exp2((s_i - s_j) * log2e/tau))
    float sum_all = 0.0f;  // sum over ALL j (self term 0.5 corrected at the end)
    float sum_pos = 0.0f;  // sum over all j of sg * target[q][j]
#pragma unroll 16
    for (int j = 0; j < B; ++j) {
        const float sj = srow[j];   // block-uniform -> s_load (SGPR)
        const float tj = trow[j];   // block-uniform -> s_load (SGPR)
        float e  = __builtin_amdgcn_exp2f(fmaf(sj, -C, sic));
        float sg = __builtin_amdgcn_rcpf(1.0f + e);
        sum_all += sg;
        sum_pos  = fmaf(sg, tj, sum_pos);
    }

    // pos_mask = target - eye: subtract the j==q sigmoid once
    {
        const float sq = srow[q];   // uniform
        float e   = __builtin_amdgcn_exp2f(fmaf(sq, -C, sic));
        float sgq = __builtin_amdgcn_rcpf(1.0f + e);
        sum_pos -= sgq;
    }

    // sim_all_rk = (sum_all - 0.5) + 1 ; sim_pos_rk = (sum_pos + t_i) * t_i
    float ratio = t_i * (sum_pos + t_i) / (sum_all + 0.5f);
    float tv    = t_i;

#pragma unroll
    for (int off = 32; off > 0; off >>= 1) {
        ratio += __shfl_down(ratio, off, 64);
        tv    += __shfl_down(tv, off, 64);
    }
    __shared__ float red_r[8];
    __shared__ float red_t[8];
    const int lane = i & 63, wid = i >> 6;
    if (lane == 0) { red_r[wid] = ratio; red_t[wid] = tv; }
    __syncthreads();
    if (i == 0) {
        float r = 0.0f, t = 0.0f;
#pragma unroll
        for (int w = 0; w < 8; ++w) { r += red_r[w]; t += red_t[w]; }
        ap_out[q] = r / t;   // ap for query q
    }
}

__global__ __launch_bounds__(512) void smoothap_final(const float* __restrict__ ap,
                                                      float* __restrict__ out) {
    float v = ap[threadIdx.x];
#pragma unroll
    for (int off = 32; off > 0; off >>= 1) v += __shfl_down(v, off, 64);
    __shared__ float red[8];
    const int lane = threadIdx.x & 63, wid = threadIdx.x >> 6;
    if (lane == 0) red[wid] = v;
    __syncthreads();
    if (threadIdx.x == 0) {
        float s = 0.0f;
#pragma unroll
        for (int w = 0; w < 8; ++w) s += red[w];
        out[0] = 1.0f - s / 512.0f;
    }
}

extern "C" void kernel_launch(void* const* d_in, const int* in_sizes, int n_in,
                              void* d_out, int out_size, void* d_ws, size_t ws_size,
                              hipStream_t stream) {
    const float* scores = (const float*)d_in[0];
    const float* target = (const float*)d_in[1];
    float* ap  = (float*)d_ws;   // 512 floats of scratch
    float* out = (float*)d_out;

    hipLaunchKernelGGL(smoothap_rows, dim3(512), dim3(512), 0, stream, scores, target, ap);
    hipLaunchKernelGGL(smoothap_final, dim3(1), dim3(512), 0, stream, ap, out);
}

// Round 3
// 87.736 us; speedup vs baseline: 1.0031x; 1.0031x over previous
//
#include <hip/hip_runtime.h>

constexpr int B = 512;
// log2(e) / tau  with tau = 0.01
constexpr float C = 144.26950408889634f;
constexpr float ACLAMP = 30.0f;   // exp2 arg clamp: sg error <= 2^-30, keeps quad product finite

// Kernel 1: partial sum over j-half of 1/(1+exp2((s_i-s_j)*C)), quad-batched rcp.
// grid = 1024 (q = bid>>1, half = bid&1), block = 512
__global__ __launch_bounds__(512) void sap_partial(const float* __restrict__ scores,
                                                   float* __restrict__ pA) {
    const int q = blockIdx.x >> 1;
    const int h = blockIdx.x & 1;
    const int i = threadIdx.x;
    __shared__ float ls[B];           // scores[q][*] * C
    const float* __restrict__ srow = scores + q * B;
    ls[i] = srow[i] * C;
    __syncthreads();
    const float sic = ls[i];

    const int j0 = h * (B / 2);
    float sum = 0.0f;                 // sum of sigmoids over this j-half (incl. self term 0.5)
#pragma unroll 4
    for (int j = j0; j < j0 + B / 2; j += 4) {
        float a0 = fminf(sic - ls[j + 0], ACLAMP);
        float a1 = fminf(sic - ls[j + 1], ACLAMP);
        float a2 = fminf(sic - ls[j + 2], ACLAMP);
        float a3 = fminf(sic - ls[j + 3], ACLAMP);
        float A0 = 1.0f + __builtin_amdgcn_exp2f(a0);
        float A1 = 1.0f + __builtin_amdgcn_exp2f(a1);
        float A2 = 1.0f + __builtin_amdgcn_exp2f(a2);
        float A3 = 1.0f + __builtin_amdgcn_exp2f(a3);
        float P01 = A0 * A1;
        float P23 = A2 * A3;
        float num = fmaf(A0 + A1, P23, (A2 + A3) * P01);   // sum of 4 reciprocals, combined
        sum = fmaf(num, __builtin_amdgcn_rcpf(P01 * P23), sum);
    }
    pA[(h * B + q) * B + i] = sum;    // coalesced store into ws
}

// Kernel 2: combine halves, compute sum_pos over compacted positive list, ratio, row-reduce.
// grid = 512 (q), block = 512
__global__ __launch_bounds__(512) void sap_combine(const float* __restrict__ scores,
                                                   const float* __restrict__ target,
                                                   const float* __restrict__ pA,
                                                   float* __restrict__ ap_out) {
    const int q = blockIdx.x;
    const int i = threadIdx.x;
    __shared__ float ls[B];
    __shared__ int plist[B];
    __shared__ int pcnt;
    __shared__ float red_r[8], red_t[8];

    const float* __restrict__ srow = scores + q * B;
    const float* __restrict__ trow = target + q * B;
    if (i == 0) pcnt = 0;
    __syncthreads();
    const float t_i = trow[i];
    ls[i] = srow[i] * C;
    if (t_i != 0.0f) { int p = atomicAdd(&pcnt, 1); plist[p] = i; }
    __syncthreads();

    const float sic = ls[i];
    const int np = pcnt;              // ~16 positives per row (incl. q itself)
    float sum_pos = 0.0f;             // sum over j with target==1 of sg(i,j)
    for (int k = 0; k < np; ++k) {
        float a = fminf(sic - ls[plist[k]], ACLAMP);
        float e = __builtin_amdgcn_exp2f(a);
        sum_pos += __builtin_amdgcn_rcpf(1.0f + e);
    }
    {   // pos_mask = target - eye: remove the j==q term
        float a = fminf(sic - ls[q], ACLAMP);
        float e = __builtin_amdgcn_exp2f(a);
        sum_pos -= __builtin_amdgcn_rcpf(1.0f + e);
    }

    // partials include self term 0.5; sim_all_rk = (sum - 0.5) + 1
    float sum_all = pA[(0 * B + q) * B + i] + pA[(1 * B + q) * B + i] + 0.5f;
    float ratio = t_i * (sum_pos + t_i) * __builtin_amdgcn_rcpf(sum_all);
    float tv = t_i;

#pragma unroll
    for (int off = 32; off > 0; off >>= 1) {
        ratio += __shfl_down(ratio, off, 64);
        tv    += __shfl_down(tv, off, 64);
    }
    const int lane = i & 63, wid = i >> 6;
    if (lane == 0) { red_r[wid] = ratio; red_t[wid] = tv; }
    __syncthreads();
    if (i == 0) {
        float r = 0.0f, t = 0.0f;
#pragma unroll
        for (int w = 0; w < 8; ++w) { r += red_r[w]; t += red_t[w]; }
        ap_out[q] = r / t;
    }
}

// Kernel 3: mean over 512 ap values -> 1 - mAP
__global__ __launch_bounds__(512) void sap_final(const float* __restrict__ ap,
                                                 float* __restrict__ out) {
    float v = ap[threadIdx.x];
#pragma unroll
    for (int off = 32; off > 0; off >>= 1) v += __shfl_down(v, off, 64);
    __shared__ float red[8];
    const int lane = threadIdx.x & 63, wid = threadIdx.x >> 6;
    if (lane == 0) red[wid] = v;
    __syncthreads();
    if (threadIdx.x == 0) {
        float s = 0.0f;
#pragma unroll
        for (int w = 0; w < 8; ++w) s += red[w];
        out[0] = 1.0f - s / 512.0f;
    }
}

extern "C" void kernel_launch(void* const* d_in, const int* in_sizes, int n_in,
                              void* d_out, int out_size, void* d_ws, size_t ws_size,
                              hipStream_t stream) {
    const float* scores = (const float*)d_in[0];
    const float* target = (const float*)d_in[1];
    float* pA  = (float*)d_ws;                    // 2 * 512 * 512 floats = 2 MB
    float* ap  = pA + 2 * B * B;                  // 512 floats
    float* out = (float*)d_out;

    hipLaunchKernelGGL(sap_partial, dim3(1024), dim3(512), 0, stream, scores, pA);
    hipLaunchKernelGGL(sap_combine, dim3(512),  dim3(512), 0, stream, scores, target, pA, ap);
    hipLaunchKernelGGL(sap_final,   dim3(1),    dim3(512), 0, stream, ap, out);
}